// Round 3
// baseline (66.554 us; speedup 1.0000x reference)
//
#include <hip/hip_runtime.h>
#include <hip/hip_bf16.h>
#include <stdint.h>

// KAN layer: out[n,o] = sum_j w[o,j] * spline(x[n,j]; coeffs[o,j,:]) + bias[o]
// N=1024, D_IN=128, D_OUT=128, K=8, Catmull-Rom, uniform grid [-1,1].
// fp32 in/out (proven R1/R2/R4).
//
// R13 POST-MORTEM: 2-kernel split = +3.05us (extra graph node ~3us). ONE launch.
// R14 POST-MORTEM: pack-shift basis + dealiased sC (-1 barrier) = -1.26us. Kept.
//
// R15 (this): ZERO-STAGING. For mfma_f32_16x16x32_bf16 with K = j*8+kk,
// lane (mo=lane&15, q=lane>>4) at K-step S needs exactly edge j = 4S+q:
//   A-frag = 8 basis weights of x[n0+mo][j]  -> pack-shift in-register
//            (the uint4 IS the fragment; identical math to R14)
//   B-frag = coeffs[o0+mo][j][0..8] * w[o0+mo][j] -> 32B + 4B load, 8 mul/cvt
// Deletes sBas/sWp (64KB), the swizzle, and the pre-MFMA __syncthreads()
// (where all 32 waves/CU drained on the slowest cold load). Same task count,
// no staging. LDS = sC 16KB only; 1 barrier total. Numerics bit-identical.
//
// MFMA 16x16x32 bf16 (R5..R14-verified): A/B-frag lane (mo=lane&15,
// q=lane>>4) holds [mo][k=32S+8q+kk]; C/D: col=lane&15, row=(lane>>4)*4+reg.

#define DIN 128
#define DOUT 128
#define KTOT 1024

typedef unsigned int u32;
typedef unsigned long long u64;
typedef unsigned short u16;
typedef __attribute__((ext_vector_type(8))) short bf16x8;
typedef __attribute__((ext_vector_type(4))) float f32x4;

union H8 { u16 s[8]; uint4 v; bf16x8 b; };

__device__ __forceinline__ u16 f2b(float f) {
    union { __hip_bfloat16 h; u16 u; } c;
    c.h = __float2bfloat16(f);   // RNE
    return c.u;
}

__global__ __launch_bounds__(1024, 8) void kan_fused(
    const float* __restrict__ x, const float* __restrict__ coeffs,
    const float* __restrict__ weights, const float* __restrict__ bias,
    float* __restrict__ out)
{
    __shared__ __align__(16) float sC[16 * 256];    // 16 KB, only LDS

    const int tid  = threadIdx.x;
    const int wave = tid >> 6;                      // 0..15 (K-sixteenth)
    const int lane = tid & 63;
    const int n0 = blockIdx.x * 16;                 // 64 m-tiles
    const int o0 = blockIdx.y * 16;                 // 8 o-tiles

    const int mo = lane & 15;
    const int q  = lane >> 4;

    const float* xrow = x       + (size_t)(n0 + mo) * DIN;
    const float* wrow = weights + (size_t)(o0 + mo) * DIN;
    const float* crow = coeffs  + (size_t)(o0 + mo) * (DIN * 8);

    f32x4 acc = {0.0f, 0.0f, 0.0f, 0.0f};
    #pragma unroll
    for (int s = 0; s < 2; ++s) {
        const int j = wave * 8 + s * 4 + q;         // edge index, 0..127

        // ---- A fragment: spline basis of x[n0+mo][j], in-register ----
        float xv = xrow[j];
        xv = fminf(fmaxf(xv, -1.0f), 1.0f);
        const float t = (xv + 1.0f) * 3.5f;         // h = 2/7
        int idx = (int)t; idx = idx > 6 ? 6 : idx;  // t>=0: trunc==floor
        const float u = t - (float)idx;
        const float u2 = u * u, u3 = u2 * u;
        const float b0 = 0.5f * (-u3 + 2.0f * u2 - u);
        const float b1 = 0.5f * (3.0f * u3 - 5.0f * u2 + 2.0f);
        const float b2 = 0.5f * (-3.0f * u3 + 4.0f * u2 + u);
        const float b3 = 0.5f * (u3 - u2);
        // Contiguous-run form of the clipped scatter (R14-verified,
        // fp32 merges first, bit-identical to accumulate-then-convert):
        //   idx==0: [b0+b1, b2, b3] at slot 0
        //   1..5 :  [b0, b1, b2, b3] at slot idx-1
        //   idx==6: [b0, b1, b2+b3] at slot 5 (b3 shifts out of 128b)
        const bool e0 = (idx == 0), e6 = (idx == 6);
        const float m0 = e0 ? b0 + b1 : b0;
        const float m1 = e0 ? b2 : b1;
        const float m2 = e0 ? b3 : (e6 ? b2 + b3 : b2);
        const float m3 = e0 ? 0.0f : b3;
        const u32 lo32 = (u32)f2b(m0) | ((u32)f2b(m1) << 16);
        const u32 hi32 = (u32)f2b(m2) | ((u32)f2b(m3) << 16);
        const u64 q64 = ((u64)hi32 << 32) | lo32;
        const int sh = e0 ? 0 : (idx - 1) * 16;     // 0..80 bits
        unsigned __int128 v128 = (unsigned __int128)q64 << sh;
        H8 a;
        a.v.x = (u32)v128;
        a.v.y = (u32)(v128 >> 32);
        a.v.z = (u32)(v128 >> 64);
        a.v.w = (u32)(v128 >> 96);

        // ---- B fragment: coeffs[o0+mo][j][:] * w[o0+mo][j], in-register ----
        const float wv = wrow[j];
        const float4 c0 = *(const float4*)(crow + j * 8);
        const float4 c1 = *(const float4*)(crow + j * 8 + 4);
        H8 b;
        b.s[0] = f2b(c0.x * wv); b.s[1] = f2b(c0.y * wv);
        b.s[2] = f2b(c0.z * wv); b.s[3] = f2b(c0.w * wv);
        b.s[4] = f2b(c1.x * wv); b.s[5] = f2b(c1.y * wv);
        b.s[6] = f2b(c1.z * wv); b.s[7] = f2b(c1.w * wv);

        acc = __builtin_amdgcn_mfma_f32_16x16x32_bf16(a.b, b.b, acc, 0, 0, 0);
    }

    // ---- 16-way K-split reduce + bias + store (R12-verified) ----
    #pragma unroll
    for (int r = 0; r < 4; ++r)
        sC[wave * 256 + (q * 4 + r) * 16 + mo] = acc[r];
    __syncthreads();

    if (tid < 256) {
        const int row = tid >> 4, col = tid & 15;
        float v = sC[tid];
        #pragma unroll
        for (int w = 1; w < 16; ++w) v += sC[w * 256 + tid];
        out[(n0 + row) * DOUT + o0 + col] = v + bias[o0 + col];
    }
}

extern "C" void kernel_launch(void* const* d_in, const int* in_sizes, int n_in,
                              void* d_out, int out_size, void* d_ws, size_t ws_size,
                              hipStream_t stream) {
    const float* x       = (const float*)d_in[0];
    const float* coeffs  = (const float*)d_in[1];
    const float* weights = (const float*)d_in[2];
    const float* bias    = (const float*)d_in[3];
    float* out = (float*)d_out;
    const int N = in_sizes[0] / DIN;                // 1024
    dim3 grid(N / 16, DOUT / 16);                   // 64 x 8 = 512 blocks
    kan_fused<<<grid, 1024, 0, stream>>>(x, coeffs, weights, bias, out);
}

// Round 4
// 61.224 us; speedup vs baseline: 1.0871x; 1.0871x over previous
//
#include <hip/hip_runtime.h>
#include <hip/hip_bf16.h>
#include <stdint.h>

// KAN layer: out[n,o] = sum_j w[o,j] * spline(x[n,j]; coeffs[o,j,:]) + bias[o]
// N=1024, D_IN=128, D_OUT=128, K=8, Catmull-Rom, uniform grid [-1,1].
// fp32 in/out (proven R1/R2/R4).
//
// R13 POST-MORTEM: 2-kernel split = +3.05us (extra graph node ~3us). ONE launch.
// R14 POST-MORTEM: pack-shift basis + dealiased sC (-1 barrier) = -1.26us. KEPT.
// R15 POST-MORTEM: zero-staging = +5.15us. The 256MB ws-poison fill evicts
//   L2/L3 every iter -> kernel runs cold; per-lane scattered loads put
//   ~900cy HBM latency on the MFMA critical path. Coalesced LDS staging is
//   structurally right; kernel is COLD-CACHE LATENCY-BOUND. Reverted.
//
// R16 (this): R14 base +
//  - XCD-aware o-tile placement: 1D grid, bx=wg>>3, by=wg&7 -> XCD(=wg%8)
//    == by. Each XCD owns ONE o-tile's 512KB coeffs slab (fetched from HBM
//    once into its private 4MB L2); all 64 blocks sharing it run there
//    (64 blocks / 32 CUs = 2/CU, balanced). Was: same-by blocks spread
//    over all 8 XCDs, slab re-fetched via L3 per XCD.
//  - issue-early loads: all 8 global loads (x*2, w*2, coeffs*4) issued at
//    the top; cold-miss latency overlaps the phase-1a spline VALU chain.
//
// MFMA 16x16x32 bf16 (R5..R14-verified): A/B-frag lane (mo=lane&15,
// q=lane>>4) holds [mo][k=32S+8q+kk]; C/D: col=lane&15, row=(lane>>4)*4+reg.

#define DIN 128
#define DOUT 128
#define KTOT 1024

typedef unsigned int u32;
typedef unsigned long long u64;
typedef unsigned short u16;
typedef __attribute__((ext_vector_type(8))) short bf16x8;
typedef __attribute__((ext_vector_type(4))) float f32x4;

union H8 { u16 s[8]; uint4 v; };

__device__ __forceinline__ u16 f2b(float f) {
    union { __hip_bfloat16 h; u16 u; } c;
    c.h = __float2bfloat16(f);   // RNE
    return c.u;
}

__global__ __launch_bounds__(1024, 8) void kan_fused(
    const float* __restrict__ x, const float* __restrict__ coeffs,
    const float* __restrict__ weights, const float* __restrict__ bias,
    float* __restrict__ out)
{
    __shared__ __align__(16) u16 sBas[16 * KTOT];   // 32 KB
    __shared__ __align__(16) u16 sWp [16 * KTOT];   // 32 KB
    __shared__ __align__(16) float sC[16 * 256];    // 16 KB

    const int tid  = threadIdx.x;
    const int wave = tid >> 6;                      // 0..15
    const int lane = tid & 63;
    const int wg = blockIdx.x;                      // 0..511 (1D)
    const int n0 = (wg >> 3) * 16;                  // 64 m-tiles
    const int o0 = (wg & 7) * 16;                   // 8 o-tiles == XCD id

    // ---- Issue ALL global loads first: overlap cold-HBM latency with
    //      the phase-1a VALU chain. Static indices only (rule #20). ----
    float xv0, xv1, wv0, wv1;
    float4 c00, c01, c10, c11;
    {
        const int t0 = tid, t1 = tid + 1024;
        xv0 = x[n0 * DIN + t0];  xv1 = x[n0 * DIN + t1];
        wv0 = weights[o0 * DIN + t0];  wv1 = weights[o0 * DIN + t1];
        c00 = *(const float4*)(coeffs + o0 * KTOT + t0 * 8);
        c01 = *(const float4*)(coeffs + o0 * KTOT + t0 * 8 + 4);
        c10 = *(const float4*)(coeffs + o0 * KTOT + t1 * 8);
        c11 = *(const float4*)(coeffs + o0 * KTOT + t1 * 8 + 4);
    }

    // ---- Phase 1a: basis tile. 2048 tasks (row,j), pack-shift build ----
    #pragma unroll
    for (int it = 0; it < 2; ++it) {
        const int task = tid + it * 1024;           // row*128 + j
        const int row = task >> 7;
        const int j = task & 127;
        float xv = it == 0 ? xv0 : xv1;
        xv = fminf(fmaxf(xv, -1.0f), 1.0f);
        const float t = (xv + 1.0f) * 3.5f;         // h = 2/7
        int idx = (int)t; idx = idx > 6 ? 6 : idx;  // t>=0: trunc==floor
        const float u = t - (float)idx;
        const float u2 = u * u, u3 = u2 * u;
        const float b0 = 0.5f * (-u3 + 2.0f * u2 - u);
        const float b1 = 0.5f * (3.0f * u3 - 5.0f * u2 + 2.0f);
        const float b2 = 0.5f * (-3.0f * u3 + 4.0f * u2 + u);
        const float b3 = 0.5f * (u3 - u2);
        // Contiguous-run form of the clipped scatter (R14-verified,
        // fp32 merges first, bit-identical to accumulate-then-convert):
        //   idx==0: [b0+b1, b2, b3] at slot 0
        //   1..5 :  [b0, b1, b2, b3] at slot idx-1
        //   idx==6: [b0, b1, b2+b3] at slot 5 (b3 shifts out of 128b)
        const bool e0 = (idx == 0), e6 = (idx == 6);
        const float m0 = e0 ? b0 + b1 : b0;
        const float m1 = e0 ? b2 : b1;
        const float m2 = e0 ? b3 : (e6 ? b2 + b3 : b2);
        const float m3 = e0 ? 0.0f : b3;
        const u32 lo32 = (u32)f2b(m0) | ((u32)f2b(m1) << 16);
        const u32 hi32 = (u32)f2b(m2) | ((u32)f2b(m3) << 16);
        const u64 q64 = ((u64)hi32 << 32) | lo32;
        const int sh = e0 ? 0 : (idx - 1) * 16;     // 0..80 bits
        unsigned __int128 v = (unsigned __int128)q64 << sh;
        uint4 stv;
        stv.x = (u32)v;
        stv.y = (u32)(v >> 32);
        stv.z = (u32)(v >> 64);
        stv.w = (u32)(v >> 96);
        const int uu = j ^ (row & 7);               // swizzled 16B unit
        *(uint4*)(sBas + row * KTOT + uu * 8) = stv;
    }

    // ---- Phase 1b: W' tile. 2048 tasks (o,j), loads already in-flight ----
    #pragma unroll
    for (int it = 0; it < 2; ++it) {
        const int task = tid + it * 1024;           // o*128 + j
        const int o = task >> 7;
        const int j = task & 127;
        const float wv = it == 0 ? wv0 : wv1;
        const float4 ca = it == 0 ? c00 : c10;
        const float4 cb = it == 0 ? c01 : c11;
        H8 h;
        h.s[0] = f2b(ca.x * wv); h.s[1] = f2b(ca.y * wv);
        h.s[2] = f2b(ca.z * wv); h.s[3] = f2b(ca.w * wv);
        h.s[4] = f2b(cb.x * wv); h.s[5] = f2b(cb.y * wv);
        h.s[6] = f2b(cb.z * wv); h.s[7] = f2b(cb.w * wv);
        const int uu = j ^ (o & 7);
        *(uint4*)(sWp + o * KTOT + uu * 8) = h.v;
    }
    __syncthreads();

    // ---- Phase 2: pure LDS MFMA, wave = K-sixteenth (2 steps) ----
    const int mo = lane & 15;
    const int q  = lane >> 4;
    const int sw = mo & 7;                          // read-side swizzle
    f32x4 acc = {0.0f, 0.0f, 0.0f, 0.0f};
    #pragma unroll
    for (int s = 0; s < 2; ++s) {
        const int S = wave * 2 + s;                 // global K-step
        const int uu = (S * 4 + q) ^ sw;            // 16B unit
        bf16x8 af = *(const bf16x8*)(sBas + mo * KTOT + uu * 8);
        bf16x8 bf = *(const bf16x8*)(sWp  + mo * KTOT + uu * 8);
        acc = __builtin_amdgcn_mfma_f32_16x16x32_bf16(af, bf, acc, 0, 0, 0);
    }
    // sC is its own LDS region -> no barrier needed before writing it.

    // ---- Phase 3: 16-way reduce + bias + store ----
    #pragma unroll
    for (int r = 0; r < 4; ++r)
        sC[wave * 256 + (q * 4 + r) * 16 + mo] = acc[r];
    __syncthreads();

    if (tid < 256) {
        const int row = tid >> 4, col = tid & 15;
        float v = sC[tid];
        #pragma unroll
        for (int w = 1; w < 16; ++w) v += sC[w * 256 + tid];
        out[(n0 + row) * DOUT + o0 + col] = v + bias[o0 + col];
    }
}

extern "C" void kernel_launch(void* const* d_in, const int* in_sizes, int n_in,
                              void* d_out, int out_size, void* d_ws, size_t ws_size,
                              hipStream_t stream) {
    const float* x       = (const float*)d_in[0];
    const float* coeffs  = (const float*)d_in[1];
    const float* weights = (const float*)d_in[2];
    const float* bias    = (const float*)d_in[3];
    float* out = (float*)d_out;
    const int N = in_sizes[0] / DIN;                // 1024
    dim3 grid((N / 16) * (DOUT / 16));              // 512 blocks, 1D:
    kan_fused<<<grid, 1024, 0, stream>>>(x, coeffs, weights, bias, out);
}